// Round 9
// baseline (191.942 us; speedup 1.0000x reference)
//
#include <hip/hip_runtime.h>

// Fused attention block for MI355X (gfx950).
// Pipeline: k_prep(conv x,W) -> GEMM1(qkv) -> k_qk(RMS/RoPE/shift) + k_vgate(gates,vT)
//           -> windowed flash attention (S^T single-pass) -> GEMM2 -> d_out (f32)

#define TSEQ 8192
#define DIMM 1024
#define NHEAD 8
#define HD 128
#define ATTN_SCALE 0.1f
#define RMS_EPS 1.1920929e-07f

typedef __bf16 bfx2 __attribute__((ext_vector_type(2)));
typedef __bf16 bfx4 __attribute__((ext_vector_type(4)));
typedef __bf16 bfx8 __attribute__((ext_vector_type(8)));
typedef float f32x4 __attribute__((ext_vector_type(4)));
typedef short s16x4 __attribute__((ext_vector_type(4)));

#define GLDS16(g, l)                                                         \
  __builtin_amdgcn_global_load_lds(                                          \
      (const __attribute__((address_space(1))) void*)(g),                    \
      (__attribute__((address_space(3))) void*)(l), 16, 0, 0)

__device__ __forceinline__ float sig_(float z) { return 1.0f / (1.0f + __expf(-z)); }

// ---------------- fused f32 -> bf16 conversions (x and weights) ----------------
__global__ void k_prep(const float4* __restrict__ x, const float4* __restrict__ w,
                       const float* __restrict__ lam, bfx4* __restrict__ xb,
                       bfx4* __restrict__ w1b, bfx4* __restrict__ w2b) {
  const int nx = TSEQ * DIMM / 4;
  const int nw = 4096 * 1024 / 4;
  const float l0 = lam[0], l1 = lam[1];
  int i = blockIdx.x * blockDim.x + threadIdx.x;
  int stride = gridDim.x * blockDim.x;
  for (; i < nx + nw; i += stride) {
    if (i < nx) {
      float4 v = x[i];
      bfx4 o;
      o[0] = (__bf16)v.x; o[1] = (__bf16)v.y; o[2] = (__bf16)v.z; o[3] = (__bf16)v.w;
      xb[i] = o;
    } else {
      int j = i - nx;
      int row = (j * 4) >> 10;
      float s = (row < 3 * DIMM) ? l0 : l1;
      float4 v = w[j];
      bfx4 o;
      o[0] = (__bf16)(s * v.x); o[1] = (__bf16)(s * v.y);
      o[2] = (__bf16)(s * v.z); o[3] = (__bf16)(s * v.w);
      if (row < 3 * DIMM) w1b[j] = o;
      else                w2b[j - 3 * DIMM * DIMM / 4] = o;
    }
  }
}

// ---------------- 2-blocks/CU GEMM: C[M,N] = A[M,K] * B[N,K]^T ----------------
// 128x128 tile, BK=64, 4 waves (2x2, wave tile 64x64), double-buffered 64KB LDS
// -> 2 blocks/CU co-resident: inter-block overlap hides the vmcnt(0)+barrier drain
// (m114/m97 mechanism). (row&7) XOR slot swizzle both-sides. XCD-chunked block swizzle.
template <typename CT>
__global__ __launch_bounds__(256, 2) void k_gemm2b(const __bf16* __restrict__ A,
                                                   const __bf16* __restrict__ B,
                                                   CT* __restrict__ C,
                                                   int M, int N, int K) {
  __shared__ __align__(16) __bf16 ldsb[2][256 * 64];  // [buf][A 128 rows | B 128 rows]
  const int tid = threadIdx.x;
  const int wave = tid >> 6, lane = tid & 63;
  const int wm = wave >> 1, wn = wave & 1;
  const int lr = lane & 15, lg = lane >> 4;

  // XCD-chunked bijective swizzle (nwg % 8 == 0 for all our grids)
  const int gx = gridDim.x;
  const int nwg = gx * gridDim.y;
  const int lid = blockIdx.y * gx + blockIdx.x;
  const int cpx = nwg >> 3;
  const int sid = (lid & 7) * cpx + (lid >> 3);
  const int bm = sid % gx, bn = sid / gx;

  const int srow = tid >> 3;                     // LDS row this thread stages (0..31 per chunk)
  const int scol = ((tid & 7) ^ (srow & 7)) * 8; // pre-swizzled global col (elems)
  const __bf16* Ag = A + (size_t)(bm * 128 + srow) * K + scol;
  const __bf16* Bg = B + (size_t)(bn * 128 + srow) * K + scol;

  char* buf0 = (char*)&ldsb[0][0];
  char* buf1 = (char*)&ldsb[1][0];

  auto stage = [&](int kt, char* buf) {
#pragma unroll
    for (int L = 0; L < 4; L++)
      GLDS16(Ag + (size_t)(L * 32) * K + kt * 64, buf + L * 4096 + wave * 1024);
#pragma unroll
    for (int L = 0; L < 4; L++)
      GLDS16(Bg + (size_t)(L * 32) * K + kt * 64, buf + 16384 + L * 4096 + wave * 1024);
  };

  const int aoffs = (wm * 64 + lr) * 128;
  const int boffs = 16384 + (wn * 64 + lr) * 128;
  const int s0 = (lg ^ (lr & 7)) * 16;
  const int s1 = ((4 + lg) ^ (lr & 7)) * 16;

  f32x4 acc[4][4] = {};

#define VMC0() asm volatile("s_waitcnt vmcnt(0)" ::: "memory")
#define BAR() __builtin_amdgcn_s_barrier()

  stage(0, buf0);
  VMC0(); BAR();

  const int NT = K / 64;
  for (int t = 0; t < NT; t++) {
    char* cur = (t & 1) ? buf1 : buf0;
    char* nxt = (t & 1) ? buf0 : buf1;
    if (t + 1 < NT) stage(t + 1, nxt);
    bfx8 af[4][2], bfr[4][2];
#pragma unroll
    for (int f = 0; f < 4; f++) {
      const char* p = cur + aoffs + f * 2048;
      af[f][0] = *(const bfx8*)(p + s0);
      af[f][1] = *(const bfx8*)(p + s1);
    }
#pragma unroll
    for (int f = 0; f < 4; f++) {
      const char* p = cur + boffs + f * 2048;
      bfr[f][0] = *(const bfx8*)(p + s0);
      bfr[f][1] = *(const bfx8*)(p + s1);
    }
    __builtin_amdgcn_s_setprio(1);
#pragma unroll
    for (int i = 0; i < 4; i++)
#pragma unroll
      for (int j = 0; j < 4; j++) {
        acc[i][j] = __builtin_amdgcn_mfma_f32_16x16x32_bf16(af[i][0], bfr[j][0], acc[i][j], 0, 0, 0);
        acc[i][j] = __builtin_amdgcn_mfma_f32_16x16x32_bf16(af[i][1], bfr[j][1], acc[i][j], 0, 0, 0);
      }
    __builtin_amdgcn_s_setprio(0);
    VMC0(); BAR();
  }

  // C/D layout: col = lane&15, row = (lane>>4)*4 + reg
  const int rbase = bm * 128 + wm * 64 + lg * 4;
  const int cbase = bn * 128 + wn * 64 + lr;
#pragma unroll
  for (int f = 0; f < 4; f++)
#pragma unroll
    for (int rr = 0; rr < 4; rr++) {
      size_t rowoff = (size_t)(rbase + f * 16 + rr) * N + cbase;
#pragma unroll
      for (int nf = 0; nf < 4; nf++) C[rowoff + nf * 16] = (CT)acc[f][nf][rr];
    }
#undef VMC0
#undef BAR
}

// ---------------- q/k postprocess: RMS, RoPE, key-offset ----------------
__global__ __launch_bounds__(512) void k_qk(
    const __bf16* __restrict__ qkv, const float* __restrict__ f1,
    const float* __restrict__ f2, const int* __restrict__ koff_p,
    __bf16* __restrict__ qb, __bf16* __restrict__ kb) {
  const int t = blockIdx.x;
  const int h = threadIdx.x >> 6;
  const int l = threadIdx.x & 63;
  const int d0 = 2 * l;
  const size_t qoff = (size_t)t * (3 * DIMM) + h * HD;

  bfx2 qv = *(const bfx2*)&qkv[qoff + d0];
  bfx2 kv = *(const bfx2*)&qkv[qoff + DIMM + d0];
  float q0 = (float)qv[0], q1 = (float)qv[1];
  float k0 = (float)kv[0], k1 = (float)kv[1];

  float sq = q0 * q0 + q1 * q1;
  float sk = k0 * k0 + k1 * k1;
#pragma unroll
  for (int off = 32; off; off >>= 1) {
    sq += __shfl_xor(sq, off);
    sk += __shfl_xor(sk, off);
  }
  float rq = rsqrtf(sq * (1.0f / 128.0f) + RMS_EPS);
  float rk = rsqrtf(sk * (1.0f / 128.0f) + RMS_EPS);
  q0 *= rq; q1 *= rq; k0 *= rk; k1 *= rk;

  float2 cc = *(const float2*)&f1[(size_t)t * HD + d0];
  float2 ss = *(const float2*)&f2[(size_t)t * HD + d0];
  float rq0 = cc.x * q0 + ss.x * q1, rq1 = cc.y * q1 + ss.y * q0;
  float rk0 = cc.x * k0 + ss.x * k1, rk1 = cc.y * k1 + ss.y * k0;

  bfx2 qo; qo[0] = (__bf16)rq0; qo[1] = (__bf16)rq1;
  *(bfx2*)&qb[(size_t)t * DIMM + h * HD + d0] = qo;

  bfx2 ko2; ko2[0] = (__bf16)rk0; ko2[1] = (__bf16)rk1;
  const int koff = *koff_p;
  const size_t kcol = (size_t)h * HD + d0;
  if (!koff || l < 32) {
    *(bfx2*)&kb[(size_t)t * DIMM + kcol] = ko2;
  } else {
    if (t + 1 < TSEQ) *(bfx2*)&kb[(size_t)(t + 1) * DIMM + kcol] = ko2;
    if (t == 0)       *(bfx2*)&kb[kcol] = ko2;
  }
}

// ---------------- v postprocess: gates + ve-gate + LDS-tiled transpose ----------------
__global__ __launch_bounds__(512) void k_vgate(
    const __bf16* __restrict__ qkv, const float* __restrict__ x,
    const float* __restrict__ ve, const float* __restrict__ agw,
    const float* __restrict__ vgw, __bf16* __restrict__ vT,
    float* __restrict__ ag) {
  __shared__ float vg_lds[64][4];
  __shared__ __bf16 vtile[HD][68];
  const int t0 = blockIdx.x * 64;
  const int hbase = blockIdx.y * 4;
  const int tid = threadIdx.x;

  if (tid < 256) {
    const int tl = tid >> 2, hh = tid & 3;
    const int h = hbase + hh;
    const int t = t0 + tl;
    float za = 0.0f, zg = 0.0f;
#pragma unroll
    for (int j = 0; j < 12; j++) {
      float xv = x[(size_t)t * DIMM + j];
      za += xv * agw[h * 12 + j];
      zg += xv * vgw[h * 12 + j];
    }
    ag[(size_t)t * NHEAD + h] = sig_(za);
    vg_lds[tl][hh] = 2.0f * sig_(zg);
  }
  __syncthreads();

  const int w = tid >> 6, l = tid & 63;
  const int dout = tid >> 2, tof = (tid & 3) * 16;
  for (int hh = 0; hh < 4; hh++) {
    const int h = hbase + hh;
#pragma unroll
    for (int it = 0; it < 8; it++) {
      const int tl = w * 8 + it;
      const int t = t0 + tl;
      const size_t voff = (size_t)t * (3 * DIMM) + 2 * DIMM + h * HD;
      float va = (float)qkv[voff + l];
      float vb = (float)qkv[voff + l + 64];
      float vea = ve[(size_t)t * DIMM + h * HD + l];
      float veb = ve[(size_t)t * DIMM + h * HD + l + 64];
      float gv = vg_lds[tl][hh];
      vtile[l][tl]      = (__bf16)(va + gv * vea);
      vtile[l + 64][tl] = (__bf16)(vb + gv * veb);
    }
    __syncthreads();
    {
      bfx4 a0 = *(const bfx4*)&vtile[dout][tof];
      bfx4 a1 = *(const bfx4*)&vtile[dout][tof + 4];
      bfx4 a2 = *(const bfx4*)&vtile[dout][tof + 8];
      bfx4 a3 = *(const bfx4*)&vtile[dout][tof + 12];
      bfx8 p0, p1;
      p0[0]=a0[0]; p0[1]=a0[1]; p0[2]=a0[2]; p0[3]=a0[3];
      p0[4]=a1[0]; p0[5]=a1[1]; p0[6]=a1[2]; p0[7]=a1[3];
      p1[0]=a2[0]; p1[1]=a2[1]; p1[2]=a2[2]; p1[3]=a2[3];
      p1[4]=a3[0]; p1[5]=a3[1]; p1[6]=a3[2]; p1[7]=a3[3];
      __bf16* dst = &vT[(size_t)(h * HD + dout) * TSEQ + t0 + tof];
      *(bfx8*)dst = p0;
      *(bfx8*)(dst + 8) = p1;
    }
    __syncthreads();
  }
}

// ---------------- windowed varlen flash attention, S^T single-pass ----------------
// grid (TSEQ/64, NHEAD); XCD-chunked so consecutive n-blocks (shared K-window) co-locate.
__global__ __launch_bounds__(256, 4) void k_attn2(
    const __bf16* __restrict__ qb, const __bf16* __restrict__ kb,
    const __bf16* __restrict__ vT, const float* __restrict__ ag,
    const int* __restrict__ sl, int ns, __bf16* __restrict__ yb) {
  const int gx = gridDim.x;
  const int nwg = gx * gridDim.y;
  const int lid = blockIdx.y * gx + blockIdx.x;
  const int cpx = nwg >> 3;
  const int sid = (lid & 7) * cpx + (lid >> 3);
  const int nb = sid % gx, h = sid / gx;

  const int w = threadIdx.x >> 6, l = threadIdx.x & 63;
  const int lr = l & 15, lg = l >> 4;
  const int q0r = (nb * 4 + w) * 16;
  const int kbase = q0r - 128;
  const int q = q0r + lr;
  const int kfs = (q0r < 128) ? ((128 - q0r) >> 4) : 0;

  bfx8 qf[4];
#pragma unroll
  for (int ds = 0; ds < 4; ds++)
    qf[ds] = *(const bfx8*)&qb[(size_t)q * DIMM + h * HD + ds * 32 + lg * 8];

  int segs = 0;
  for (int i = 0; i < ns; i++) {
    int v = sl[i];
    segs = (v <= q) ? ((v > segs) ? v : segs) : segs;
  }
  int klo = q - 128;
  if (segs > klo) klo = segs;
  if (klo < 0) klo = 0;

  f32x4 sf[9] = {};
#pragma unroll
  for (int kf = 0; kf < 9; kf++) {
    if (kf >= kfs) {
      const int krow = kbase + kf * 16 + lr;
      const __bf16* kp = &kb[(size_t)krow * DIMM + h * HD + lg * 8];
      bfx8 k0 = *(const bfx8*)(kp);
      bfx8 k1 = *(const bfx8*)(kp + 32);
      bfx8 k2 = *(const bfx8*)(kp + 64);
      bfx8 k3 = *(const bfx8*)(kp + 96);
      sf[kf] = __builtin_amdgcn_mfma_f32_16x16x32_bf16(k0, qf[0], sf[kf], 0, 0, 0);
      sf[kf] = __builtin_amdgcn_mfma_f32_16x16x32_bf16(k1, qf[1], sf[kf], 0, 0, 0);
      sf[kf] = __builtin_amdgcn_mfma_f32_16x16x32_bf16(k2, qf[2], sf[kf], 0, 0, 0);
      sf[kf] = __builtin_amdgcn_mfma_f32_16x16x32_bf16(k3, qf[3], sf[kf], 0, 0, 0);
    }
  }

#pragma unroll
  for (int kf = 0; kf < 9; kf++)
#pragma unroll
    for (int rr = 0; rr < 4; rr++) {
      int k = kbase + kf * 16 + lg * 4 + rr;
      bool valid = (k >= klo) && (k <= q);
      sf[kf][rr] = valid ? sf[kf][rr] * ATTN_SCALE : -1e30f;
    }

  float mx = -1e30f;
#pragma unroll
  for (int kf = 0; kf < 9; kf++)
#pragma unroll
    for (int rr = 0; rr < 4; rr++) mx = fmaxf(mx, sf[kf][rr]);
  mx = fmaxf(mx, __shfl_xor(mx, 16));
  mx = fmaxf(mx, __shfl_xor(mx, 32));

  float lsum = 0.0f;
#pragma unroll
  for (int kf = 0; kf < 9; kf++)
#pragma unroll
    for (int rr = 0; rr < 4; rr++) {
      float p = __expf(sf[kf][rr] - mx);
      sf[kf][rr] = p;
      lsum += p;
    }
  lsum += __shfl_xor(lsum, 16);
  lsum += __shfl_xor(lsum, 32);

  f32x4 o[8] = {};
#pragma unroll
  for (int kf = 0; kf < 9; kf++) {
    if (kf >= kfs) {
      bfx4 pc;
      pc[0] = (__bf16)sf[kf][0]; pc[1] = (__bf16)sf[kf][1];
      pc[2] = (__bf16)sf[kf][2]; pc[3] = (__bf16)sf[kf][3];
      s16x4 pb = *(s16x4*)&pc;
      const int kk = kbase + kf * 16 + 4 * lg;
#pragma unroll
      for (int nf = 0; nf < 8; nf++) {
        s16x4 vf = *(const s16x4*)&vT[(size_t)(h * HD + nf * 16 + lr) * TSEQ + kk];
        o[nf] = __builtin_amdgcn_mfma_f32_16x16x16bf16_1k(vf, pb, o[nf], 0, 0, 0);
      }
    }
  }

  const float sc = ag[(size_t)q * NHEAD + h] / lsum;
#pragma unroll
  for (int nf = 0; nf < 8; nf++) {
    bfx4 st;
#pragma unroll
    for (int rr = 0; rr < 4; rr++) st[rr] = (__bf16)(o[nf][rr] * sc);
    *(bfx4*)&yb[(size_t)q * DIMM + h * HD + nf * 16 + lg * 4] = st;
  }
}

// ---------------- launch ----------------
extern "C" void kernel_launch(void* const* d_in, const int* in_sizes, int n_in,
                              void* d_out, int out_size, void* d_ws, size_t ws_size,
                              hipStream_t stream) {
  const float* x   = (const float*)d_in[0];
  const float* qw  = (const float*)d_in[1];
  const float* ve  = (const float*)d_in[2];
  const float* lam = (const float*)d_in[3];
  const float* f1  = (const float*)d_in[4];
  const float* f2  = (const float*)d_in[5];
  const float* agw = (const float*)d_in[6];
  const float* vgw = (const float*)d_in[7];
  const int*   sl  = (const int*)d_in[8];
  const int    ns  = in_sizes[8];
  const int*   koff = (const int*)d_in[10];
  float* out = (float*)d_out;
  char* ws = (char*)d_ws;

  // workspace layout (bytes):
  // [0,16M) xb (later aliased by vT) | [16M,22M) w1b | [22M,24M) w2b |
  // [24M,72M) qkvb (later ybuf) | [72M,88M) qbuf | [88M,104M) kbuf | [104M,+) ag
  const size_t MB = 1024 * 1024;
  if (ws_size < 105 * MB) return;
  __bf16* xb   = (__bf16*)(ws);
  __bf16* w1b  = (__bf16*)(ws + 16 * MB);
  __bf16* w2b  = (__bf16*)(ws + 22 * MB);
  __bf16* qkvb = (__bf16*)(ws + 24 * MB);
  __bf16* qbuf = (__bf16*)(ws + 72 * MB);
  __bf16* kbuf = (__bf16*)(ws + 88 * MB);
  float*  ag   = (float*)(ws + 104 * MB);
  __bf16* vT   = xb;    // xb dead after GEMM1
  __bf16* ybuf = qkvb;  // qkvb dead after k_qk/k_vgate

  k_prep<<<3072, 256, 0, stream>>>((const float4*)x, (const float4*)qw, lam,
                                   (bfx4*)xb, (bfx4*)w1b, (bfx4*)w2b);
  k_gemm2b<__bf16><<<dim3(TSEQ / 128, 3 * DIMM / 128), 256, 0, stream>>>(
      xb, w1b, qkvb, TSEQ, 3 * DIMM, DIMM);
  k_qk<<<TSEQ, 512, 0, stream>>>(qkvb, f1, f2, koff, qbuf, kbuf);
  k_vgate<<<dim3(TSEQ / 64, 2), 512, 0, stream>>>(qkvb, x, ve, agw, vgw, vT, ag);
  k_attn2<<<dim3(TSEQ / 64, NHEAD), 256, 0, stream>>>(qbuf, kbuf, vT, ag, sl, ns, ybuf);
  k_gemm2b<float><<<dim3(TSEQ / 128, DIMM / 128), 256, 0, stream>>>(
      ybuf, w2b, out, TSEQ, DIMM, DIMM);
}

// Round 10
// 171.176 us; speedup vs baseline: 1.1213x; 1.1213x over previous
//
#include <hip/hip_runtime.h>
#include <type_traits>

// Fused attention block for MI355X (gfx950).
// Pipeline: k_prep(conv x,W) -> GEMM1(qkv, 2-blk/CU dbuf) -> k_qk + k_vgate ->
//           windowed flash attention (S^T single-pass) -> GEMM2 (8-phase) -> d_out

#define TSEQ 8192
#define DIMM 1024
#define NHEAD 8
#define HD 128
#define ATTN_SCALE 0.1f
#define RMS_EPS 1.1920929e-07f

typedef __bf16 bfx2 __attribute__((ext_vector_type(2)));
typedef __bf16 bfx4 __attribute__((ext_vector_type(4)));
typedef __bf16 bfx8 __attribute__((ext_vector_type(8)));
typedef float f32x4 __attribute__((ext_vector_type(4)));
typedef short s16x4 __attribute__((ext_vector_type(4)));

#define GLDS16(g, l)                                                         \
  __builtin_amdgcn_global_load_lds(                                          \
      (const __attribute__((address_space(1))) void*)(g),                    \
      (__attribute__((address_space(3))) void*)(l), 16, 0, 0)

__device__ __forceinline__ float sig_(float z) { return 1.0f / (1.0f + __expf(-z)); }

// ---------------- fused f32 -> bf16 conversions (x and weights) ----------------
__global__ void k_prep(const float4* __restrict__ x, const float4* __restrict__ w,
                       const float* __restrict__ lam, bfx4* __restrict__ xb,
                       bfx4* __restrict__ w1b, bfx4* __restrict__ w2b) {
  const int nx = TSEQ * DIMM / 4;
  const int nw = 4096 * 1024 / 4;
  const float l0 = lam[0], l1 = lam[1];
  int i = blockIdx.x * blockDim.x + threadIdx.x;
  int stride = gridDim.x * blockDim.x;
  for (; i < nx + nw; i += stride) {
    if (i < nx) {
      float4 v = x[i];
      bfx4 o;
      o[0] = (__bf16)v.x; o[1] = (__bf16)v.y; o[2] = (__bf16)v.z; o[3] = (__bf16)v.w;
      xb[i] = o;
    } else {
      int j = i - nx;
      int row = (j * 4) >> 10;
      float s = (row < 3 * DIMM) ? l0 : l1;
      float4 v = w[j];
      bfx4 o;
      o[0] = (__bf16)(s * v.x); o[1] = (__bf16)(s * v.y);
      o[2] = (__bf16)(s * v.z); o[3] = (__bf16)(s * v.w);
      if (row < 3 * DIMM) w1b[j] = o;
      else                w2b[j - 3 * DIMM * DIMM / 4] = o;
    }
  }
}

// ---------------- 2-blocks/CU GEMM: C[M,N] = A[M,K] * B[N,K]^T ----------------
// 128x128 tile, BK=64, 4 waves (2x2, wave tile 64x64), double-buffered 64KB LDS
// -> 2 blocks/CU co-resident (inter-block overlap, m114 mechanism). No block swizzle
// (default dispatch order gives B-tile L2/L3 reuse). (row&7) XOR swizzle both-sides.
template <typename CT>
__global__ __launch_bounds__(256, 2) void k_gemm2b(const __bf16* __restrict__ A,
                                                   const __bf16* __restrict__ B,
                                                   CT* __restrict__ C,
                                                   int M, int N, int K) {
  __shared__ __align__(16) __bf16 ldsb[2][256 * 64];  // [buf][A 128 rows | B 128 rows]
  const int tid = threadIdx.x;
  const int wave = tid >> 6, lane = tid & 63;
  const int wm = wave >> 1, wn = wave & 1;
  const int lr = lane & 15, lg = lane >> 4;
  const int bm = blockIdx.x, bn = blockIdx.y;

  const int srow = tid >> 3;                     // LDS row staged (0..31 per chunk)
  const int scol = ((tid & 7) ^ (srow & 7)) * 8; // pre-swizzled global col (elems)
  const __bf16* Ag = A + (size_t)(bm * 128 + srow) * K + scol;
  const __bf16* Bg = B + (size_t)(bn * 128 + srow) * K + scol;

  char* buf0 = (char*)&ldsb[0][0];
  char* buf1 = (char*)&ldsb[1][0];

  auto stage = [&](int kt, char* buf) {
#pragma unroll
    for (int L = 0; L < 4; L++)
      GLDS16(Ag + (size_t)(L * 32) * K + kt * 64, buf + L * 4096 + wave * 1024);
#pragma unroll
    for (int L = 0; L < 4; L++)
      GLDS16(Bg + (size_t)(L * 32) * K + kt * 64, buf + 16384 + L * 4096 + wave * 1024);
  };

  const int aoffs = (wm * 64 + lr) * 128;
  const int boffs = 16384 + (wn * 64 + lr) * 128;
  const int s0 = (lg ^ (lr & 7)) * 16;
  const int s1 = ((4 + lg) ^ (lr & 7)) * 16;

  f32x4 acc[4][4] = {};

#define VMC0() asm volatile("s_waitcnt vmcnt(0)" ::: "memory")
#define BAR() __builtin_amdgcn_s_barrier()

  stage(0, buf0);
  VMC0(); BAR();

  const int NT = K / 64;
  for (int t = 0; t < NT; t++) {
    char* cur = (t & 1) ? buf1 : buf0;
    char* nxt = (t & 1) ? buf0 : buf1;
    if (t + 1 < NT) stage(t + 1, nxt);
    bfx8 af[4][2], bfr[4][2];
#pragma unroll
    for (int f = 0; f < 4; f++) {
      const char* p = cur + aoffs + f * 2048;
      af[f][0] = *(const bfx8*)(p + s0);
      af[f][1] = *(const bfx8*)(p + s1);
    }
#pragma unroll
    for (int f = 0; f < 4; f++) {
      const char* p = cur + boffs + f * 2048;
      bfr[f][0] = *(const bfx8*)(p + s0);
      bfr[f][1] = *(const bfx8*)(p + s1);
    }
    __builtin_amdgcn_s_setprio(1);
#pragma unroll
    for (int i = 0; i < 4; i++)
#pragma unroll
      for (int j = 0; j < 4; j++) {
        acc[i][j] = __builtin_amdgcn_mfma_f32_16x16x32_bf16(af[i][0], bfr[j][0], acc[i][j], 0, 0, 0);
        acc[i][j] = __builtin_amdgcn_mfma_f32_16x16x32_bf16(af[i][1], bfr[j][1], acc[i][j], 0, 0, 0);
      }
    __builtin_amdgcn_s_setprio(0);
    VMC0(); BAR();
  }

  const int rbase = bm * 128 + wm * 64 + lg * 4;
  const int cbase = bn * 128 + wn * 64 + lr;
#pragma unroll
  for (int f = 0; f < 4; f++)
#pragma unroll
    for (int rr = 0; rr < 4; rr++) {
      size_t rowoff = (size_t)(rbase + f * 16 + rr) * N + cbase;
#pragma unroll
      for (int nf = 0; nf < 4; nf++) C[rowoff + nf * 16] = (CT)acc[f][nf][rr];
    }
#undef VMC0
#undef BAR
}

// ---------------- interleaved 8-phase GEMM (r7-proven; used for GEMM2) ----------------
template <int BM, typename CT>
__global__ __launch_bounds__(512, 2) void k_gemm8i(const __bf16* __restrict__ A,
                                                   const __bf16* __restrict__ B,
                                                   CT* __restrict__ C,
                                                   int M, int N, int K) {
  constexpr int MF = BM / 32, NF = 4;
  constexpr int MH = MF / 2;
  constexpr int LA = BM / 128, LB = 2;
  __shared__ __align__(16) __bf16 lds0s[(BM + 256) * 64];
  __shared__ __align__(16) __bf16 lds1s[(BM + 256) * 64];
  char* lds0 = (char*)lds0s;
  char* lds1 = (char*)lds1s;

  const int tid = threadIdx.x;
  const int wave = tid >> 6, lane = tid & 63;
  const int wm = wave >> 2, wn = wave & 3;
  const int lr = lane & 15, lg = lane >> 4;
  const int bm = blockIdx.x, bn = blockIdx.y;

  const int srow = tid >> 3;
  const int scol = ((tid & 7) ^ (srow & 7)) * 8;
  const __bf16* Ag = A + (size_t)(bm * BM + srow) * K + scol;
  const __bf16* Bg = B + (size_t)(bn * 256 + srow) * K + scol;

  auto stageAu = [&](int kt, int u, char* buf) {
#pragma unroll
    for (int L = 0; L < LA; L++)
      GLDS16(Ag + (size_t)(u * (BM / 2) + L * 64) * K + kt * 64,
             buf + (u * (BM / 2) + L * 64) * 128 + wave * 1024);
  };
  auto stageBu = [&](int kt, int u, char* buf) {
#pragma unroll
    for (int L = 0; L < LB; L++)
      GLDS16(Bg + (size_t)(u * 128 + L * 64) * K + kt * 64,
             buf + BM * 128 + (u * 128 + L * 64) * 128 + wave * 1024);
  };

  const int aoffs = (wm * (BM / 2) + lr) * 128;
  const int boffs = BM * 128 + (wn * 64 + lr) * 128;
  const int s0 = (lg ^ (lr & 7)) * 16;
  const int s1 = ((4 + lg) ^ (lr & 7)) * 16;

  f32x4 acc[MF][4] = {};
  bfx8 af[MH][2], bfr[4][2];

  auto readAf = [&](int i, const char* rbuf, int hf) {
    const char* p = rbuf + aoffs + (hf * MH + i) * 2048;
    af[i][0] = *(const bfx8*)(p + s0);
    af[i][1] = *(const bfx8*)(p + s1);
  };
  auto readBf = [&](int f, const char* rbuf) {
    const char* p = rbuf + boffs + f * 2048;
    bfr[f][0] = *(const bfx8*)(p + s0);
    bfr[f][1] = *(const bfx8*)(p + s1);
  };
  auto mfma2 = [&](int ha, int hb, int i, int j) {
    acc[ha * MH + i][hb * 2 + j] = __builtin_amdgcn_mfma_f32_16x16x32_bf16(
        af[i][0], bfr[hb * 2 + j][0], acc[ha * MH + i][hb * 2 + j], 0, 0, 0);
    acc[ha * MH + i][hb * 2 + j] = __builtin_amdgcn_mfma_f32_16x16x32_bf16(
        af[i][1], bfr[hb * 2 + j][1], acc[ha * MH + i][hb * 2 + j], 0, 0, 0);
  };
  auto clusterPlain = [&](int ha, int hb) {
    __builtin_amdgcn_s_setprio(1);
#pragma unroll
    for (int i = 0; i < MH; i++) { mfma2(ha, hb, i, 0); mfma2(ha, hb, i, 1); }
    __builtin_amdgcn_s_setprio(0);
  };
  auto clusterA_r = [&](int ha, int hb, const char* rbuf, int hf) {
    __builtin_amdgcn_s_setprio(1);
#pragma unroll
    for (int i = 0; i < MH; i++) {
      mfma2(ha, hb, i, 0); mfma2(ha, hb, i, 1);
      readAf(i, rbuf, hf);
      __builtin_amdgcn_sched_group_barrier(0x8, 4, 0);
      __builtin_amdgcn_sched_group_barrier(0x100, 2, 0);
    }
    __builtin_amdgcn_s_setprio(0);
  };
  auto clusterB_r = [&](int ha, int hb, const char* rbuf) {
    __builtin_amdgcn_s_setprio(1);
#pragma unroll
    for (int j = 0; j < 2; j++) {
#pragma unroll
      for (int i = 0; i < MH; i++) mfma2(ha, hb, i, j);
      readBf(hb * 2 + j, rbuf);
      __builtin_amdgcn_sched_group_barrier(0x8, MH * 2, 0);
      __builtin_amdgcn_sched_group_barrier(0x100, 2, 0);
    }
    __builtin_amdgcn_s_setprio(0);
  };

#define BAR() __builtin_amdgcn_s_barrier()
#define VMC(n) asm volatile("s_waitcnt vmcnt(%0)" ::"i"(n) : "memory")

  stageAu(0, 0, lds0); stageAu(0, 1, lds0);
  stageBu(0, 0, lds0); stageBu(0, 1, lds0);
  stageBu(1, 0, lds1); stageBu(1, 1, lds1);
  VMC(2 * LB); BAR();
#pragma unroll
  for (int i = 0; i < MH; i++) readAf(i, lds0, 0);
#pragma unroll
  for (int f = 0; f < 4; f++) readBf(f, lds0);

  int jj = 0;
  auto run_iter = [&](auto more_c) {
    constexpr bool more = decltype(more_c)::value;
    const int t1 = 2 * jj + 1, t2 = t1 + 1, t3 = t1 + 2;
    stageAu(t1, 0, lds1);
    clusterPlain(0, 0);
    BAR();
    stageAu(t1, 1, lds1);
    clusterA_r(0, 1, lds0, 1);
    VMC(2 * LA); BAR();
    if constexpr (more) stageBu(t2, 0, lds0);
    clusterB_r(1, 0, lds1);
    VMC(more ? LB : 0); BAR();
    if constexpr (more) stageBu(t2, 1, lds0);
    clusterA_r(1, 1, lds1, 0);
    readBf(2, lds1); readBf(3, lds1);
    BAR();
    if constexpr (more) stageAu(t2, 0, lds0);
    clusterPlain(0, 0);
    BAR();
    if constexpr (more) stageAu(t2, 1, lds0);
    clusterA_r(0, 1, lds1, 1);
    if constexpr (more) { VMC(2 * LA); }
    BAR();
    if constexpr (more) {
      stageBu(t3, 0, lds1);
      clusterB_r(1, 0, lds0);
      VMC(LB);
    } else {
      clusterPlain(1, 0);
    }
    BAR();
    if constexpr (more) {
      stageBu(t3, 1, lds1);
      clusterA_r(1, 1, lds0, 0);
      readBf(2, lds0); readBf(3, lds0);
    } else {
      clusterPlain(1, 1);
    }
    BAR();
    jj++;
  };

  const int NT2 = K / 128;
  for (int j = 0; j < NT2 - 1; j++) run_iter(std::integral_constant<bool, true>{});
  run_iter(std::integral_constant<bool, false>{});

  const int rbase = bm * BM + wm * (BM / 2) + lg * 4;
  const int cbase = bn * 256 + wn * 64 + lr;
#pragma unroll
  for (int f = 0; f < MF; f++)
#pragma unroll
    for (int rr = 0; rr < 4; rr++) {
      size_t rowoff = (size_t)(rbase + f * 16 + rr) * N + cbase;
#pragma unroll
      for (int nf = 0; nf < 4; nf++) C[rowoff + nf * 16] = (CT)acc[f][nf][rr];
    }
#undef BAR
#undef VMC
}

// ---------------- q/k postprocess: RMS, RoPE, key-offset ----------------
__global__ __launch_bounds__(512) void k_qk(
    const __bf16* __restrict__ qkv, const float* __restrict__ f1,
    const float* __restrict__ f2, const int* __restrict__ koff_p,
    __bf16* __restrict__ qb, __bf16* __restrict__ kb) {
  const int t = blockIdx.x;
  const int h = threadIdx.x >> 6;
  const int l = threadIdx.x & 63;
  const int d0 = 2 * l;
  const size_t qoff = (size_t)t * (3 * DIMM) + h * HD;

  bfx2 qv = *(const bfx2*)&qkv[qoff + d0];
  bfx2 kv = *(const bfx2*)&qkv[qoff + DIMM + d0];
  float q0 = (float)qv[0], q1 = (float)qv[1];
  float k0 = (float)kv[0], k1 = (float)kv[1];

  float sq = q0 * q0 + q1 * q1;
  float sk = k0 * k0 + k1 * k1;
#pragma unroll
  for (int off = 32; off; off >>= 1) {
    sq += __shfl_xor(sq, off);
    sk += __shfl_xor(sk, off);
  }
  float rq = rsqrtf(sq * (1.0f / 128.0f) + RMS_EPS);
  float rk = rsqrtf(sk * (1.0f / 128.0f) + RMS_EPS);
  q0 *= rq; q1 *= rq; k0 *= rk; k1 *= rk;

  float2 cc = *(const float2*)&f1[(size_t)t * HD + d0];
  float2 ss = *(const float2*)&f2[(size_t)t * HD + d0];
  float rq0 = cc.x * q0 + ss.x * q1, rq1 = cc.y * q1 + ss.y * q0;
  float rk0 = cc.x * k0 + ss.x * k1, rk1 = cc.y * k1 + ss.y * k0;

  bfx2 qo; qo[0] = (__bf16)rq0; qo[1] = (__bf16)rq1;
  *(bfx2*)&qb[(size_t)t * DIMM + h * HD + d0] = qo;

  bfx2 ko2; ko2[0] = (__bf16)rk0; ko2[1] = (__bf16)rk1;
  const int koff = *koff_p;
  const size_t kcol = (size_t)h * HD + d0;
  if (!koff || l < 32) {
    *(bfx2*)&kb[(size_t)t * DIMM + kcol] = ko2;
  } else {
    if (t + 1 < TSEQ) *(bfx2*)&kb[(size_t)(t + 1) * DIMM + kcol] = ko2;
    if (t == 0)       *(bfx2*)&kb[kcol] = ko2;
  }
}

// ---------------- v postprocess: gates + ve-gate + LDS-tiled transpose ----------------
__global__ __launch_bounds__(512) void k_vgate(
    const __bf16* __restrict__ qkv, const float* __restrict__ x,
    const float* __restrict__ ve, const float* __restrict__ agw,
    const float* __restrict__ vgw, __bf16* __restrict__ vT,
    float* __restrict__ ag) {
  __shared__ float vg_lds[64][4];
  __shared__ __bf16 vtile[HD][68];
  const int t0 = blockIdx.x * 64;
  const int hbase = blockIdx.y * 4;
  const int tid = threadIdx.x;

  if (tid < 256) {
    const int tl = tid >> 2, hh = tid & 3;
    const int h = hbase + hh;
    const int t = t0 + tl;
    float za = 0.0f, zg = 0.0f;
#pragma unroll
    for (int j = 0; j < 12; j++) {
      float xv = x[(size_t)t * DIMM + j];
      za += xv * agw[h * 12 + j];
      zg += xv * vgw[h * 12 + j];
    }
    ag[(size_t)t * NHEAD + h] = sig_(za);
    vg_lds[tl][hh] = 2.0f * sig_(zg);
  }
  __syncthreads();

  const int w = tid >> 6, l = tid & 63;
  const int dout = tid >> 2, tof = (tid & 3) * 16;
  for (int hh = 0; hh < 4; hh++) {
    const int h = hbase + hh;
#pragma unroll
    for (int it = 0; it < 8; it++) {
      const int tl = w * 8 + it;
      const int t = t0 + tl;
      const size_t voff = (size_t)t * (3 * DIMM) + 2 * DIMM + h * HD;
      float va = (float)qkv[voff + l];
      float vb = (float)qkv[voff + l + 64];
      float vea = ve[(size_t)t * DIMM + h * HD + l];
      float veb = ve[(size_t)t * DIMM + h * HD + l + 64];
      float gv = vg_lds[tl][hh];
      vtile[l][tl]      = (__bf16)(va + gv * vea);
      vtile[l + 64][tl] = (__bf16)(vb + gv * veb);
    }
    __syncthreads();
    {
      bfx4 a0 = *(const bfx4*)&vtile[dout][tof];
      bfx4 a1 = *(const bfx4*)&vtile[dout][tof + 4];
      bfx4 a2 = *(const bfx4*)&vtile[dout][tof + 8];
      bfx4 a3 = *(const bfx4*)&vtile[dout][tof + 12];
      bfx8 p0, p1;
      p0[0]=a0[0]; p0[1]=a0[1]; p0[2]=a0[2]; p0[3]=a0[3];
      p0[4]=a1[0]; p0[5]=a1[1]; p0[6]=a1[2]; p0[7]=a1[3];
      p1[0]=a2[0]; p1[1]=a2[1]; p1[2]=a2[2]; p1[3]=a2[3];
      p1[4]=a3[0]; p1[5]=a3[1]; p1[6]=a3[2]; p1[7]=a3[3];
      __bf16* dst = &vT[(size_t)(h * HD + dout) * TSEQ + t0 + tof];
      *(bfx8*)dst = p0;
      *(bfx8*)(dst + 8) = p1;
    }
    __syncthreads();
  }
}

// ---------------- windowed varlen flash attention, S^T single-pass ----------------
__global__ __launch_bounds__(256, 4) void k_attn2(
    const __bf16* __restrict__ qb, const __bf16* __restrict__ kb,
    const __bf16* __restrict__ vT, const float* __restrict__ ag,
    const int* __restrict__ sl, int ns, __bf16* __restrict__ yb) {
  const int h = blockIdx.y;
  const int w = threadIdx.x >> 6, l = threadIdx.x & 63;
  const int lr = l & 15, lg = l >> 4;
  const int q0r = (blockIdx.x * 4 + w) * 16;
  const int kbase = q0r - 128;
  const int q = q0r + lr;
  const int kfs = (q0r < 128) ? ((128 - q0r) >> 4) : 0;

  bfx8 qf[4];
#pragma unroll
  for (int ds = 0; ds < 4; ds++)
    qf[ds] = *(const bfx8*)&qb[(size_t)q * DIMM + h * HD + ds * 32 + lg * 8];

  int segs = 0;
  for (int i = 0; i < ns; i++) {
    int v = sl[i];
    segs = (v <= q) ? ((v > segs) ? v : segs) : segs;
  }
  int klo = q - 128;
  if (segs > klo) klo = segs;
  if (klo < 0) klo = 0;

  f32x4 sf[9] = {};
#pragma unroll
  for (int kf = 0; kf < 9; kf++) {
    if (kf >= kfs) {
      const int krow = kbase + kf * 16 + lr;
      const __bf16* kp = &kb[(size_t)krow * DIMM + h * HD + lg * 8];
      bfx8 k0 = *(const bfx8*)(kp);
      bfx8 k1 = *(const bfx8*)(kp + 32);
      bfx8 k2 = *(const bfx8*)(kp + 64);
      bfx8 k3 = *(const bfx8*)(kp + 96);
      sf[kf] = __builtin_amdgcn_mfma_f32_16x16x32_bf16(k0, qf[0], sf[kf], 0, 0, 0);
      sf[kf] = __builtin_amdgcn_mfma_f32_16x16x32_bf16(k1, qf[1], sf[kf], 0, 0, 0);
      sf[kf] = __builtin_amdgcn_mfma_f32_16x16x32_bf16(k2, qf[2], sf[kf], 0, 0, 0);
      sf[kf] = __builtin_amdgcn_mfma_f32_16x16x32_bf16(k3, qf[3], sf[kf], 0, 0, 0);
    }
  }

#pragma unroll
  for (int kf = 0; kf < 9; kf++)
#pragma unroll
    for (int rr = 0; rr < 4; rr++) {
      int k = kbase + kf * 16 + lg * 4 + rr;
      bool valid = (k >= klo) && (k <= q);
      sf[kf][rr] = valid ? sf[kf][rr] * ATTN_SCALE : -1e30f;
    }

  float mx = -1e30f;
#pragma unroll
  for (int kf = 0; kf < 9; kf++)
#pragma unroll
    for (int rr = 0; rr < 4; rr++) mx = fmaxf(mx, sf[kf][rr]);
  mx = fmaxf(mx, __shfl_xor(mx, 16));
  mx = fmaxf(mx, __shfl_xor(mx, 32));

  float lsum = 0.0f;
#pragma unroll
  for (int kf = 0; kf < 9; kf++)
#pragma unroll
    for (int rr = 0; rr < 4; rr++) {
      float p = __expf(sf[kf][rr] - mx);
      sf[kf][rr] = p;
      lsum += p;
    }
  lsum += __shfl_xor(lsum, 16);
  lsum += __shfl_xor(lsum, 32);

  f32x4 o[8] = {};
#pragma unroll
  for (int kf = 0; kf < 9; kf++) {
    if (kf >= kfs) {
      bfx4 pc;
      pc[0] = (__bf16)sf[kf][0]; pc[1] = (__bf16)sf[kf][1];
      pc[2] = (__bf16)sf[kf][2]; pc[3] = (__bf16)sf[kf][3];
      s16x4 pb = *(s16x4*)&pc;
      const int kk = kbase + kf * 16 + 4 * lg;
#pragma unroll
      for (int nf = 0; nf < 8; nf++) {
        s16x4 vf = *(const s16x4*)&vT[(size_t)(h * HD + nf * 16 + lr) * TSEQ + kk];
        o[nf] = __builtin_amdgcn_mfma_f32_16x16x16bf16_1k(vf, pb, o[nf], 0, 0, 0);
      }
    }
  }

  const float sc = ag[(size_t)q * NHEAD + h] / lsum;
#pragma unroll
  for (int nf = 0; nf < 8; nf++) {
    bfx4 st;
#pragma unroll
    for (int rr = 0; rr < 4; rr++) st[rr] = (__bf16)(o[nf][rr] * sc);
    *(bfx4*)&yb[(size_t)q * DIMM + h * HD + nf * 16 + lg * 4] = st;
  }
}

// ---------------- launch ----------------
extern "C" void kernel_launch(void* const* d_in, const int* in_sizes, int n_in,
                              void* d_out, int out_size, void* d_ws, size_t ws_size,
                              hipStream_t stream) {
  const float* x   = (const float*)d_in[0];
  const float* qw  = (const float*)d_in[1];
  const float* ve  = (const float*)d_in[2];
  const float* lam = (const float*)d_in[3];
  const float* f1  = (const float*)d_in[4];
  const float* f2  = (const float*)d_in[5];
  const float* agw = (const float*)d_in[6];
  const float* vgw = (const float*)d_in[7];
  const int*   sl  = (const int*)d_in[8];
  const int    ns  = in_sizes[8];
  const int*   koff = (const int*)d_in[10];
  float* out = (float*)d_out;
  char* ws = (char*)d_ws;

  // workspace layout (bytes):
  // [0,16M) xb (later aliased by vT) | [16M,22M) w1b | [22M,24M) w2b |
  // [24M,72M) qkvb (later ybuf) | [72M,88M) qbuf | [88M,104M) kbuf | [104M,+) ag
  const size_t MB = 1024 * 1024;
  if (ws_size < 105 * MB) return;
  __bf16* xb   = (__bf16*)(ws);
  __bf16* w1b  = (__bf16*)(ws + 16 * MB);
  __bf16* w2b  = (__bf16*)(ws + 22 * MB);
  __bf16* qkvb = (__bf16*)(ws + 24 * MB);
  __bf16* qbuf = (__bf16*)(ws + 72 * MB);
  __bf16* kbuf = (__bf16*)(ws + 88 * MB);
  float*  ag   = (float*)(ws + 104 * MB);
  __bf16* vT   = xb;    // xb dead after GEMM1
  __bf16* ybuf = qkvb;  // qkvb dead after k_qk/k_vgate

  k_prep<<<3072, 256, 0, stream>>>((const float4*)x, (const float4*)qw, lam,
                                   (bfx4*)xb, (bfx4*)w1b, (bfx4*)w2b);
  k_gemm2b<__bf16><<<dim3(TSEQ / 128, 3 * DIMM / 128), 256, 0, stream>>>(
      xb, w1b, qkvb, TSEQ, 3 * DIMM, DIMM);
  k_qk<<<TSEQ, 512, 0, stream>>>(qkvb, f1, f2, koff, qbuf, kbuf);
  k_vgate<<<dim3(TSEQ / 64, 2), 512, 0, stream>>>(qkvb, x, ve, agw, vgw, vT, ag);
  k_attn2<<<dim3(TSEQ / 64, NHEAD), 256, 0, stream>>>(qbuf, kbuf, vT, ag, sl, ns, ybuf);
  k_gemm8i<128, float><<<dim3(TSEQ / 128, DIMM / 256), 512, 0, stream>>>(
      ybuf, w2b, out, TSEQ, DIMM, DIMM);
}

// Round 11
// 143.453 us; speedup vs baseline: 1.3380x; 1.1933x over previous
//
#include <hip/hip_runtime.h>
#include <type_traits>

// Fused attention block for MI355X (gfx950).
// Pipeline: k_prep(conv x,W) -> GEMM1(qkv, 2-blk/CU dbuf) -> k_qk + k_vgate ->
//           LDS-staged windowed flash attention -> GEMM2 (8-phase) -> d_out

#define TSEQ 8192
#define DIMM 1024
#define NHEAD 8
#define HD 128
#define ATTN_SCALE 0.1f
#define RMS_EPS 1.1920929e-07f

typedef __bf16 bfx2 __attribute__((ext_vector_type(2)));
typedef __bf16 bfx4 __attribute__((ext_vector_type(4)));
typedef __bf16 bfx8 __attribute__((ext_vector_type(8)));
typedef float f32x4 __attribute__((ext_vector_type(4)));
typedef short s16x4 __attribute__((ext_vector_type(4)));

#define GLDS16(g, l)                                                         \
  __builtin_amdgcn_global_load_lds(                                          \
      (const __attribute__((address_space(1))) void*)(g),                    \
      (__attribute__((address_space(3))) void*)(l), 16, 0, 0)

__device__ __forceinline__ float sig_(float z) { return 1.0f / (1.0f + __expf(-z)); }

// ---------------- fused f32 -> bf16 conversions (x and weights) ----------------
__global__ void k_prep(const float4* __restrict__ x, const float4* __restrict__ w,
                       const float* __restrict__ lam, bfx4* __restrict__ xb,
                       bfx4* __restrict__ w1b, bfx4* __restrict__ w2b) {
  const int nx = TSEQ * DIMM / 4;
  const int nw = 4096 * 1024 / 4;
  const float l0 = lam[0], l1 = lam[1];
  int i = blockIdx.x * blockDim.x + threadIdx.x;
  int stride = gridDim.x * blockDim.x;
  for (; i < nx + nw; i += stride) {
    if (i < nx) {
      float4 v = x[i];
      bfx4 o;
      o[0] = (__bf16)v.x; o[1] = (__bf16)v.y; o[2] = (__bf16)v.z; o[3] = (__bf16)v.w;
      xb[i] = o;
    } else {
      int j = i - nx;
      int row = (j * 4) >> 10;
      float s = (row < 3 * DIMM) ? l0 : l1;
      float4 v = w[j];
      bfx4 o;
      o[0] = (__bf16)(s * v.x); o[1] = (__bf16)(s * v.y);
      o[2] = (__bf16)(s * v.z); o[3] = (__bf16)(s * v.w);
      if (row < 3 * DIMM) w1b[j] = o;
      else                w2b[j - 3 * DIMM * DIMM / 4] = o;
    }
  }
}

// ---------------- 2-blocks/CU GEMM: C[M,N] = A[M,K] * B[N,K]^T ----------------
// 128x128 tile, BK=64, 4 waves (2x2), double-buffered 64KB LDS -> 2 blocks/CU.
template <typename CT>
__global__ __launch_bounds__(256, 2) void k_gemm2b(const __bf16* __restrict__ A,
                                                   const __bf16* __restrict__ B,
                                                   CT* __restrict__ C,
                                                   int M, int N, int K) {
  __shared__ __align__(16) __bf16 ldsb[2][256 * 64];
  const int tid = threadIdx.x;
  const int wave = tid >> 6, lane = tid & 63;
  const int wm = wave >> 1, wn = wave & 1;
  const int lr = lane & 15, lg = lane >> 4;
  const int bm = blockIdx.x, bn = blockIdx.y;

  const int srow = tid >> 3;
  const int scol = ((tid & 7) ^ (srow & 7)) * 8;
  const __bf16* Ag = A + (size_t)(bm * 128 + srow) * K + scol;
  const __bf16* Bg = B + (size_t)(bn * 128 + srow) * K + scol;

  char* buf0 = (char*)&ldsb[0][0];
  char* buf1 = (char*)&ldsb[1][0];

  auto stage = [&](int kt, char* buf) {
#pragma unroll
    for (int L = 0; L < 4; L++)
      GLDS16(Ag + (size_t)(L * 32) * K + kt * 64, buf + L * 4096 + wave * 1024);
#pragma unroll
    for (int L = 0; L < 4; L++)
      GLDS16(Bg + (size_t)(L * 32) * K + kt * 64, buf + 16384 + L * 4096 + wave * 1024);
  };

  const int aoffs = (wm * 64 + lr) * 128;
  const int boffs = 16384 + (wn * 64 + lr) * 128;
  const int s0 = (lg ^ (lr & 7)) * 16;
  const int s1 = ((4 + lg) ^ (lr & 7)) * 16;

  f32x4 acc[4][4] = {};

#define VMC0() asm volatile("s_waitcnt vmcnt(0)" ::: "memory")
#define BAR() __builtin_amdgcn_s_barrier()

  stage(0, buf0);
  VMC0(); BAR();

  const int NT = K / 64;
  for (int t = 0; t < NT; t++) {
    char* cur = (t & 1) ? buf1 : buf0;
    char* nxt = (t & 1) ? buf0 : buf1;
    if (t + 1 < NT) stage(t + 1, nxt);
    bfx8 af[4][2], bfr[4][2];
#pragma unroll
    for (int f = 0; f < 4; f++) {
      const char* p = cur + aoffs + f * 2048;
      af[f][0] = *(const bfx8*)(p + s0);
      af[f][1] = *(const bfx8*)(p + s1);
    }
#pragma unroll
    for (int f = 0; f < 4; f++) {
      const char* p = cur + boffs + f * 2048;
      bfr[f][0] = *(const bfx8*)(p + s0);
      bfr[f][1] = *(const bfx8*)(p + s1);
    }
    __builtin_amdgcn_s_setprio(1);
#pragma unroll
    for (int i = 0; i < 4; i++)
#pragma unroll
      for (int j = 0; j < 4; j++) {
        acc[i][j] = __builtin_amdgcn_mfma_f32_16x16x32_bf16(af[i][0], bfr[j][0], acc[i][j], 0, 0, 0);
        acc[i][j] = __builtin_amdgcn_mfma_f32_16x16x32_bf16(af[i][1], bfr[j][1], acc[i][j], 0, 0, 0);
      }
    __builtin_amdgcn_s_setprio(0);
    VMC0(); BAR();
  }

  const int rbase = bm * 128 + wm * 64 + lg * 4;
  const int cbase = bn * 128 + wn * 64 + lr;
#pragma unroll
  for (int f = 0; f < 4; f++)
#pragma unroll
    for (int rr = 0; rr < 4; rr++) {
      size_t rowoff = (size_t)(rbase + f * 16 + rr) * N + cbase;
#pragma unroll
      for (int nf = 0; nf < 4; nf++) C[rowoff + nf * 16] = (CT)acc[f][nf][rr];
    }
#undef VMC0
#undef BAR
}

// ---------------- interleaved 8-phase GEMM (r7-proven; used for GEMM2) ----------------
template <int BM, typename CT>
__global__ __launch_bounds__(512, 2) void k_gemm8i(const __bf16* __restrict__ A,
                                                   const __bf16* __restrict__ B,
                                                   CT* __restrict__ C,
                                                   int M, int N, int K) {
  constexpr int MF = BM / 32, NF = 4;
  constexpr int MH = MF / 2;
  constexpr int LA = BM / 128, LB = 2;
  __shared__ __align__(16) __bf16 lds0s[(BM + 256) * 64];
  __shared__ __align__(16) __bf16 lds1s[(BM + 256) * 64];
  char* lds0 = (char*)lds0s;
  char* lds1 = (char*)lds1s;

  const int tid = threadIdx.x;
  const int wave = tid >> 6, lane = tid & 63;
  const int wm = wave >> 2, wn = wave & 3;
  const int lr = lane & 15, lg = lane >> 4;
  const int bm = blockIdx.x, bn = blockIdx.y;

  const int srow = tid >> 3;
  const int scol = ((tid & 7) ^ (srow & 7)) * 8;
  const __bf16* Ag = A + (size_t)(bm * BM + srow) * K + scol;
  const __bf16* Bg = B + (size_t)(bn * 256 + srow) * K + scol;

  auto stageAu = [&](int kt, int u, char* buf) {
#pragma unroll
    for (int L = 0; L < LA; L++)
      GLDS16(Ag + (size_t)(u * (BM / 2) + L * 64) * K + kt * 64,
             buf + (u * (BM / 2) + L * 64) * 128 + wave * 1024);
  };
  auto stageBu = [&](int kt, int u, char* buf) {
#pragma unroll
    for (int L = 0; L < LB; L++)
      GLDS16(Bg + (size_t)(u * 128 + L * 64) * K + kt * 64,
             buf + BM * 128 + (u * 128 + L * 64) * 128 + wave * 1024);
  };

  const int aoffs = (wm * (BM / 2) + lr) * 128;
  const int boffs = BM * 128 + (wn * 64 + lr) * 128;
  const int s0 = (lg ^ (lr & 7)) * 16;
  const int s1 = ((4 + lg) ^ (lr & 7)) * 16;

  f32x4 acc[MF][4] = {};
  bfx8 af[MH][2], bfr[4][2];

  auto readAf = [&](int i, const char* rbuf, int hf) {
    const char* p = rbuf + aoffs + (hf * MH + i) * 2048;
    af[i][0] = *(const bfx8*)(p + s0);
    af[i][1] = *(const bfx8*)(p + s1);
  };
  auto readBf = [&](int f, const char* rbuf) {
    const char* p = rbuf + boffs + f * 2048;
    bfr[f][0] = *(const bfx8*)(p + s0);
    bfr[f][1] = *(const bfx8*)(p + s1);
  };
  auto mfma2 = [&](int ha, int hb, int i, int j) {
    acc[ha * MH + i][hb * 2 + j] = __builtin_amdgcn_mfma_f32_16x16x32_bf16(
        af[i][0], bfr[hb * 2 + j][0], acc[ha * MH + i][hb * 2 + j], 0, 0, 0);
    acc[ha * MH + i][hb * 2 + j] = __builtin_amdgcn_mfma_f32_16x16x32_bf16(
        af[i][1], bfr[hb * 2 + j][1], acc[ha * MH + i][hb * 2 + j], 0, 0, 0);
  };
  auto clusterPlain = [&](int ha, int hb) {
    __builtin_amdgcn_s_setprio(1);
#pragma unroll
    for (int i = 0; i < MH; i++) { mfma2(ha, hb, i, 0); mfma2(ha, hb, i, 1); }
    __builtin_amdgcn_s_setprio(0);
  };
  auto clusterA_r = [&](int ha, int hb, const char* rbuf, int hf) {
    __builtin_amdgcn_s_setprio(1);
#pragma unroll
    for (int i = 0; i < MH; i++) {
      mfma2(ha, hb, i, 0); mfma2(ha, hb, i, 1);
      readAf(i, rbuf, hf);
      __builtin_amdgcn_sched_group_barrier(0x8, 4, 0);
      __builtin_amdgcn_sched_group_barrier(0x100, 2, 0);
    }
    __builtin_amdgcn_s_setprio(0);
  };
  auto clusterB_r = [&](int ha, int hb, const char* rbuf) {
    __builtin_amdgcn_s_setprio(1);
#pragma unroll
    for (int j = 0; j < 2; j++) {
#pragma unroll
      for (int i = 0; i < MH; i++) mfma2(ha, hb, i, j);
      readBf(hb * 2 + j, rbuf);
      __builtin_amdgcn_sched_group_barrier(0x8, MH * 2, 0);
      __builtin_amdgcn_sched_group_barrier(0x100, 2, 0);
    }
    __builtin_amdgcn_s_setprio(0);
  };

#define BAR() __builtin_amdgcn_s_barrier()
#define VMC(n) asm volatile("s_waitcnt vmcnt(%0)" ::"i"(n) : "memory")

  stageAu(0, 0, lds0); stageAu(0, 1, lds0);
  stageBu(0, 0, lds0); stageBu(0, 1, lds0);
  stageBu(1, 0, lds1); stageBu(1, 1, lds1);
  VMC(2 * LB); BAR();
#pragma unroll
  for (int i = 0; i < MH; i++) readAf(i, lds0, 0);
#pragma unroll
  for (int f = 0; f < 4; f++) readBf(f, lds0);

  int jj = 0;
  auto run_iter = [&](auto more_c) {
    constexpr bool more = decltype(more_c)::value;
    const int t1 = 2 * jj + 1, t2 = t1 + 1, t3 = t1 + 2;
    stageAu(t1, 0, lds1);
    clusterPlain(0, 0);
    BAR();
    stageAu(t1, 1, lds1);
    clusterA_r(0, 1, lds0, 1);
    VMC(2 * LA); BAR();
    if constexpr (more) stageBu(t2, 0, lds0);
    clusterB_r(1, 0, lds1);
    VMC(more ? LB : 0); BAR();
    if constexpr (more) stageBu(t2, 1, lds0);
    clusterA_r(1, 1, lds1, 0);
    readBf(2, lds1); readBf(3, lds1);
    BAR();
    if constexpr (more) stageAu(t2, 0, lds0);
    clusterPlain(0, 0);
    BAR();
    if constexpr (more) stageAu(t2, 1, lds0);
    clusterA_r(0, 1, lds1, 1);
    if constexpr (more) { VMC(2 * LA); }
    BAR();
    if constexpr (more) {
      stageBu(t3, 0, lds1);
      clusterB_r(1, 0, lds0);
      VMC(LB);
    } else {
      clusterPlain(1, 0);
    }
    BAR();
    if constexpr (more) {
      stageBu(t3, 1, lds1);
      clusterA_r(1, 1, lds0, 0);
      readBf(2, lds0); readBf(3, lds0);
    } else {
      clusterPlain(1, 1);
    }
    BAR();
    jj++;
  };

  const int NT2 = K / 128;
  for (int j = 0; j < NT2 - 1; j++) run_iter(std::integral_constant<bool, true>{});
  run_iter(std::integral_constant<bool, false>{});

  const int rbase = bm * BM + wm * (BM / 2) + lg * 4;
  const int cbase = bn * 256 + wn * 64 + lr;
#pragma unroll
  for (int f = 0; f < MF; f++)
#pragma unroll
    for (int rr = 0; rr < 4; rr++) {
      size_t rowoff = (size_t)(rbase + f * 16 + rr) * N + cbase;
#pragma unroll
      for (int nf = 0; nf < 4; nf++) C[rowoff + nf * 16] = (CT)acc[f][nf][rr];
    }
#undef BAR
#undef VMC
}

// ---------------- q/k postprocess: RMS, RoPE, key-offset ----------------
__global__ __launch_bounds__(512) void k_qk(
    const __bf16* __restrict__ qkv, const float* __restrict__ f1,
    const float* __restrict__ f2, const int* __restrict__ koff_p,
    __bf16* __restrict__ qb, __bf16* __restrict__ kb) {
  const int t = blockIdx.x;
  const int h = threadIdx.x >> 6;
  const int l = threadIdx.x & 63;
  const int d0 = 2 * l;
  const size_t qoff = (size_t)t * (3 * DIMM) + h * HD;

  bfx2 qv = *(const bfx2*)&qkv[qoff + d0];
  bfx2 kv = *(const bfx2*)&qkv[qoff + DIMM + d0];
  float q0 = (float)qv[0], q1 = (float)qv[1];
  float k0 = (float)kv[0], k1 = (float)kv[1];

  float sq = q0 * q0 + q1 * q1;
  float sk = k0 * k0 + k1 * k1;
#pragma unroll
  for (int off = 32; off; off >>= 1) {
    sq += __shfl_xor(sq, off);
    sk += __shfl_xor(sk, off);
  }
  float rq = rsqrtf(sq * (1.0f / 128.0f) + RMS_EPS);
  float rk = rsqrtf(sk * (1.0f / 128.0f) + RMS_EPS);
  q0 *= rq; q1 *= rq; k0 *= rk; k1 *= rk;

  float2 cc = *(const float2*)&f1[(size_t)t * HD + d0];
  float2 ss = *(const float2*)&f2[(size_t)t * HD + d0];
  float rq0 = cc.x * q0 + ss.x * q1, rq1 = cc.y * q1 + ss.y * q0;
  float rk0 = cc.x * k0 + ss.x * k1, rk1 = cc.y * k1 + ss.y * k0;

  bfx2 qo; qo[0] = (__bf16)rq0; qo[1] = (__bf16)rq1;
  *(bfx2*)&qb[(size_t)t * DIMM + h * HD + d0] = qo;

  bfx2 ko2; ko2[0] = (__bf16)rk0; ko2[1] = (__bf16)rk1;
  const int koff = *koff_p;
  const size_t kcol = (size_t)h * HD + d0;
  if (!koff || l < 32) {
    *(bfx2*)&kb[(size_t)t * DIMM + kcol] = ko2;
  } else {
    if (t + 1 < TSEQ) *(bfx2*)&kb[(size_t)(t + 1) * DIMM + kcol] = ko2;
    if (t == 0)       *(bfx2*)&kb[kcol] = ko2;
  }
}

// ---------------- v postprocess: gates + ve-gate + LDS-tiled transpose ----------------
__global__ __launch_bounds__(512) void k_vgate(
    const __bf16* __restrict__ qkv, const float* __restrict__ x,
    const float* __restrict__ ve, const float* __restrict__ agw,
    const float* __restrict__ vgw, __bf16* __restrict__ vT,
    float* __restrict__ ag) {
  __shared__ float vg_lds[64][4];
  __shared__ __bf16 vtile[HD][68];
  const int t0 = blockIdx.x * 64;
  const int hbase = blockIdx.y * 4;
  const int tid = threadIdx.x;

  if (tid < 256) {
    const int tl = tid >> 2, hh = tid & 3;
    const int h = hbase + hh;
    const int t = t0 + tl;
    float za = 0.0f, zg = 0.0f;
#pragma unroll
    for (int j = 0; j < 12; j++) {
      float xv = x[(size_t)t * DIMM + j];
      za += xv * agw[h * 12 + j];
      zg += xv * vgw[h * 12 + j];
    }
    ag[(size_t)t * NHEAD + h] = sig_(za);
    vg_lds[tl][hh] = 2.0f * sig_(zg);
  }
  __syncthreads();

  const int w = tid >> 6, l = tid & 63;
  const int dout = tid >> 2, tof = (tid & 3) * 16;
  for (int hh = 0; hh < 4; hh++) {
    const int h = hbase + hh;
#pragma unroll
    for (int it = 0; it < 8; it++) {
      const int tl = w * 8 + it;
      const int t = t0 + tl;
      const size_t voff = (size_t)t * (3 * DIMM) + 2 * DIMM + h * HD;
      float va = (float)qkv[voff + l];
      float vb = (float)qkv[voff + l + 64];
      float vea = ve[(size_t)t * DIMM + h * HD + l];
      float veb = ve[(size_t)t * DIMM + h * HD + l + 64];
      float gv = vg_lds[tl][hh];
      vtile[l][tl]      = (__bf16)(va + gv * vea);
      vtile[l + 64][tl] = (__bf16)(vb + gv * veb);
    }
    __syncthreads();
    {
      bfx4 a0 = *(const bfx4*)&vtile[dout][tof];
      bfx4 a1 = *(const bfx4*)&vtile[dout][tof + 4];
      bfx4 a2 = *(const bfx4*)&vtile[dout][tof + 8];
      bfx4 a3 = *(const bfx4*)&vtile[dout][tof + 12];
      bfx8 p0, p1;
      p0[0]=a0[0]; p0[1]=a0[1]; p0[2]=a0[2]; p0[3]=a0[3];
      p0[4]=a1[0]; p0[5]=a1[1]; p0[6]=a1[2]; p0[7]=a1[3];
      p1[0]=a2[0]; p1[1]=a2[1]; p1[2]=a2[2]; p1[3]=a2[3];
      p1[4]=a3[0]; p1[5]=a3[1]; p1[6]=a3[2]; p1[7]=a3[3];
      __bf16* dst = &vT[(size_t)(h * HD + dout) * TSEQ + t0 + tof];
      *(bfx8*)dst = p0;
      *(bfx8*)(dst + 8) = p1;
    }
    __syncthreads();
  }
}

// ---------------- LDS-staged windowed varlen flash attention ----------------
// grid (TSEQ/128, NHEAD), 512 threads (8 waves); wave w owns q rows [n*128+w*16, +16).
// Block stages K window [n*128-128, +256) (64KB, swizzled) and vT window (64KB),
// then per-wave compute identical to the verified S^T single-pass kernel.
__global__ __launch_bounds__(512, 1) void k_attn3(
    const __bf16* __restrict__ qb, const __bf16* __restrict__ kb,
    const __bf16* __restrict__ vT, const float* __restrict__ ag,
    const int* __restrict__ sl, int ns, __bf16* __restrict__ yb) {
  __shared__ __align__(16) char kls[65536];  // K: 256 rows x 256B (swizzled slots)
  __shared__ __align__(16) char vls[65536];  // V: 128 d-rows x 512B (swizzled slots)
  const int n = blockIdx.x, h = blockIdx.y;
  const int tid = threadIdx.x;
  const int w = tid >> 6, l = tid & 63;
  const int lr = l & 15, lg = l >> 4;
  const int q0r = n * 128 + w * 16;
  const int kbase = q0r - 128;      // wave key base (global)
  const int kbb = n * 128 - 128;    // block key base (global)
  const int q = q0r + lr;
  const int kfs = (q0r < 128) ? ((128 - q0r) >> 4) : 0;

  // Q fragments (global, drained by the staging vmcnt)
  bfx8 qf[4];
#pragma unroll
  for (int ds = 0; ds < 4; ds++)
    qf[ds] = *(const bfx8*)&qb[(size_t)q * DIMM + h * HD + ds * 32 + lg * 8];

  // ---- stage K: 8 rounds x 8KB; lane covers (rel row, 16B slot) ----
  {
    const int rr_ = tid >> 4;      // relative row within 32-row group
    const int slot = tid & 15;
#pragma unroll
    for (int r = 0; r < 8; r++) {
      const int rel = r * 32 + rr_;                  // 0..255 block-relative row
      int grow = kbb + rel;
      grow = grow < 0 ? 0 : grow;                    // clamp (masked later)
      const int slotp = slot ^ (rel & 15);           // pre-swizzled source slot
      GLDS16(kb + (size_t)grow * DIMM + h * HD + slotp * 8,
             kls + r * 8192 + w * 1024);
    }
  }
  // ---- stage V: 8 rounds x 8KB; lane covers (d row, 16B slot of 32) ----
  {
    const int slot = l & 31;
#pragma unroll
    for (int r = 0; r < 8; r++) {
      const int d = r * 16 + w * 2 + (l >> 5);       // 0..127
      const int slotp = slot ^ (d & 15);             // 4-bit XOR within 32 slots
      int tsrc = kbb + slotp * 8;
      tsrc = tsrc < 0 ? 0 : tsrc;                    // clamp (masked later)
      GLDS16(vT + (size_t)(h * HD + d) * TSEQ + tsrc,
             vls + r * 8192 + w * 1024);
    }
  }

  // segment lower bound per q-row
  int segs = 0;
  for (int i = 0; i < ns; i++) {
    int v = sl[i];
    segs = (v <= q) ? ((v > segs) ? v : segs) : segs;
  }
  int klo = q - 128;
  if (segs > klo) klo = segs;
  if (klo < 0) klo = 0;

  asm volatile("s_waitcnt vmcnt(0)" ::: "memory");
  __builtin_amdgcn_s_barrier();

  // ---- S^T = K Q^T over the 144-key window (K frags from LDS) ----
  const int kswz = lr << 4;  // per-lane constant XOR (rel row & 15 == lr)
  f32x4 sf[9] = {};
#pragma unroll
  for (int kf = 0; kf < 9; kf++) {
    if (kf >= kfs) {
      const int relrow = w * 16 + kf * 16 + lr;
      const char* kp = kls + relrow * 256;
      bfx8 k0 = *(const bfx8*)(kp + ((lg * 16) ^ kswz));
      bfx8 k1 = *(const bfx8*)(kp + ((64 + lg * 16) ^ kswz));
      bfx8 k2 = *(const bfx8*)(kp + ((128 + lg * 16) ^ kswz));
      bfx8 k3 = *(const bfx8*)(kp + ((192 + lg * 16) ^ kswz));
      sf[kf] = __builtin_amdgcn_mfma_f32_16x16x32_bf16(k0, qf[0], sf[kf], 0, 0, 0);
      sf[kf] = __builtin_amdgcn_mfma_f32_16x16x32_bf16(k1, qf[1], sf[kf], 0, 0, 0);
      sf[kf] = __builtin_amdgcn_mfma_f32_16x16x32_bf16(k2, qf[2], sf[kf], 0, 0, 0);
      sf[kf] = __builtin_amdgcn_mfma_f32_16x16x32_bf16(k3, qf[3], sf[kf], 0, 0, 0);
    }
  }

  // mask + scale
#pragma unroll
  for (int kf = 0; kf < 9; kf++)
#pragma unroll
    for (int rr = 0; rr < 4; rr++) {
      int k = kbase + kf * 16 + lg * 4 + rr;
      bool valid = (k >= klo) && (k <= q);
      sf[kf][rr] = valid ? sf[kf][rr] * ATTN_SCALE : -1e30f;
    }

  float mx = -1e30f;
#pragma unroll
  for (int kf = 0; kf < 9; kf++)
#pragma unroll
    for (int rr = 0; rr < 4; rr++) mx = fmaxf(mx, sf[kf][rr]);
  mx = fmaxf(mx, __shfl_xor(mx, 16));
  mx = fmaxf(mx, __shfl_xor(mx, 32));

  float lsum = 0.0f;
#pragma unroll
  for (int kf = 0; kf < 9; kf++)
#pragma unroll
    for (int rr = 0; rr < 4; rr++) {
      float p = __expf(sf[kf][rr] - mx);
      sf[kf][rr] = p;
      lsum += p;
    }
  lsum += __shfl_xor(lsum, 16);
  lsum += __shfl_xor(lsum, 32);

  // ---- O^T = V^T P^T via 16x16x16 MFMAs (V frags from LDS) ----
  f32x4 o[8] = {};
#pragma unroll
  for (int kf = 0; kf < 9; kf++) {
    if (kf >= kfs) {
      bfx4 pc;
      pc[0] = (__bf16)sf[kf][0]; pc[1] = (__bf16)sf[kf][1];
      pc[2] = (__bf16)sf[kf][2]; pc[3] = (__bf16)sf[kf][3];
      s16x4 pb = *(s16x4*)&pc;
      const int tof = (w * 32 + kf * 32 + lg * 8) ^ kswz;  // swizzled t-byte
#pragma unroll
      for (int nf = 0; nf < 8; nf++) {
        s16x4 vf = *(const s16x4*)(vls + (nf * 16 + lr) * 512 + tof);
        o[nf] = __builtin_amdgcn_mfma_f32_16x16x16bf16_1k(vf, pb, o[nf], 0, 0, 0);
      }
    }
  }

  const float sc = ag[(size_t)q * NHEAD + h] / lsum;
#pragma unroll
  for (int nf = 0; nf < 8; nf++) {
    bfx4 st;
#pragma unroll
    for (int rr = 0; rr < 4; rr++) st[rr] = (__bf16)(o[nf][rr] * sc);
    *(bfx4*)&yb[(size_t)q * DIMM + h * HD + nf * 16 + lg * 4] = st;
  }
}

// ---------------- launch ----------------
extern "C" void kernel_launch(void* const* d_in, const int* in_sizes, int n_in,
                              void* d_out, int out_size, void* d_ws, size_t ws_size,
                              hipStream_t stream) {
  const float* x   = (const float*)d_in[0];
  const float* qw  = (const float*)d_in[1];
  const float* ve  = (const float*)d_in[2];
  const float* lam = (const float*)d_in[3];
  const float* f1  = (const float*)d_in[4];
  const float* f2  = (const float*)d_in[5];
  const float* agw = (const float*)d_in[6];
  const float* vgw = (const float*)d_in[7];
  const int*   sl  = (const int*)d_in[8];
  const int    ns  = in_sizes[8];
  const int*   koff = (const int*)d_in[10];
  float* out = (float*)d_out;
  char* ws = (char*)d_ws;

  const size_t MB = 1024 * 1024;
  if (ws_size < 105 * MB) return;
  __bf16* xb   = (__bf16*)(ws);
  __bf16* w1b  = (__bf16*)(ws + 16 * MB);
  __bf16* w2b  = (__bf16*)(ws + 22 * MB);
  __bf16* qkvb = (__bf16*)(ws + 24 * MB);
  __bf16* qbuf = (__bf16*)(ws + 72 * MB);
  __bf16* kbuf = (__bf16*)(ws + 88 * MB);
  float*  ag   = (float*)(ws + 104 * MB);
  __bf16* vT   = xb;    // xb dead after GEMM1
  __bf16* ybuf = qkvb;  // qkvb dead after k_qk/k_vgate

  k_prep<<<3072, 256, 0, stream>>>((const float4*)x, (const float4*)qw, lam,
                                   (bfx4*)xb, (bfx4*)w1b, (bfx4*)w2b);
  k_gemm2b<__bf16><<<dim3(TSEQ / 128, 3 * DIMM / 128), 256, 0, stream>>>(
      xb, w1b, qkvb, TSEQ, 3 * DIMM, DIMM);
  k_qk<<<TSEQ, 512, 0, stream>>>(qkvb, f1, f2, koff, qbuf, kbuf);
  k_vgate<<<dim3(TSEQ / 64, 2), 512, 0, stream>>>(qkvb, x, ve, agw, vgw, vT, ag);
  k_attn3<<<dim3(TSEQ / 128, NHEAD), 512, 0, stream>>>(qbuf, kbuf, vT, ag, sl, ns, ybuf);
  k_gemm8i<128, float><<<dim3(TSEQ / 128, DIMM / 256), 512, 0, stream>>>(
      ybuf, w2b, out, TSEQ, DIMM, DIMM);
}